// Round 2
// baseline (2178.472 us; speedup 1.0000x reference)
//
#include <hip/hip_runtime.h>
#include <hip/hip_bf16.h>
#include <cstdint>
#include <cstddef>

#define NN 50000
#define NE 800000
#define ETOT (NN + NE)   // 850000 edges incl. self loops

typedef float f32x4 __attribute__((ext_vector_type(4)));
typedef short s16x8 __attribute__((ext_vector_type(8)));
typedef unsigned short u16x8 __attribute__((ext_vector_type(8)));

__device__ __forceinline__ unsigned short f2bf(float f) {
  unsigned u = __float_as_uint(f);
  u += 0x7FFFu + ((u >> 16) & 1u);   // round-to-nearest-even
  return (unsigned short)(u >> 16);
}
// order-preserving float<->uint map for atomicMax on floats (memset-0 == -inf floor)
__device__ __forceinline__ unsigned fenc(float f) {
  unsigned u = __float_as_uint(f);
  return (u & 0x80000000u) ? ~u : (u | 0x80000000u);
}
__device__ __forceinline__ float fdec(unsigned u) {
  return __uint_as_float((u & 0x80000000u) ? (u & 0x7FFFFFFFu) : ~u);
}

// edge_index may arrive as int32 or int64 (reference uses jnp.int64; harness may
// or may not downcast). A detect kernel writes flag=1 if the buffer is int64.
__global__ void detect_i64(const void* __restrict__ ei, int* __restrict__ flag) {
  const long long v = ((const long long*)ei)[threadIdx.x];
  const bool ok = (v >= 0 && v < NN);
  const unsigned long long m = __ballot(ok);
  if (threadIdx.x == 0) *flag = (m == ~0ULL) ? 1 : 0;
}

__device__ __forceinline__ void load_edge(const void* __restrict__ ei, int is64,
                                          int eidx, int& src, int& dst) {
  if (eidx >= NE) { src = dst = eidx - NE; return; }   // self loops appended
  if (is64) {
    src = (int)((const long long*)ei)[eidx];
    dst = (int)((const long long*)ei)[NE + eidx];
  } else {
    src = ((const int*)ei)[eidx];
    dst = ((const int*)ei)[NE + eidx];
  }
}

// ---------------- GEMM: C[M][Ncols] = A_f32[M][K] @ BT_bf16[Ncols][K]^T (+bias) ----
// 128x64 tile, 4 waves, BK=32, mfma_f32_16x16x32_bf16. A converted fp32->bf16 in staging.
#define BM 128
#define BN 64
#define BK 32
#define LDK 40   // 32 + 8 shorts pad (16B-aligned rows, spreads LDS banks)

__global__ __launch_bounds__(256) void gemm_kernel(
    const float* __restrict__ A, const unsigned short* __restrict__ BT,
    float* __restrict__ C, const float* __restrict__ bias,
    int M, int K, int Ncols)
{
  __shared__ unsigned short As[BM][LDK];
  __shared__ unsigned short Bs[BN][LDK];
  const int tid  = threadIdx.x;
  const int wave = tid >> 6;
  const int lane = tid & 63;
  const int l16  = lane & 15;
  const int lq   = lane >> 4;
  const int col0 = blockIdx.x * BN;   // x = col panel (fast) -> A-panel L2 reuse
  const int row0 = blockIdx.y * BM;

  const int arow  = tid >> 1;
  const int ahalf = tid & 1;
  int ag = row0 + arow; if (ag > M - 1) ag = M - 1;   // clamp; OOB rows masked at store
  const float* aptr = A + (size_t)ag * K + ahalf * 16;
  const int brow   = tid >> 2;
  const int bchunk = tid & 3;
  const unsigned short* bptr = BT + (size_t)(col0 + brow) * K + bchunk * 8;

  f32x4 acc[2][4];
  #pragma unroll
  for (int i = 0; i < 2; ++i)
    #pragma unroll
    for (int j = 0; j < 4; ++j)
      #pragma unroll
      for (int r = 0; r < 4; ++r) acc[i][j][r] = 0.f;

  for (int k0 = 0; k0 < K; k0 += BK) {
    const float4* ap = (const float4*)(aptr + k0);
    float4 f0 = ap[0], f1 = ap[1], f2v = ap[2], f3 = ap[3];
    u16x8 v0, v1;
    v0[0]=f2bf(f0.x); v0[1]=f2bf(f0.y); v0[2]=f2bf(f0.z); v0[3]=f2bf(f0.w);
    v0[4]=f2bf(f1.x); v0[5]=f2bf(f1.y); v0[6]=f2bf(f1.z); v0[7]=f2bf(f1.w);
    v1[0]=f2bf(f2v.x); v1[1]=f2bf(f2v.y); v1[2]=f2bf(f2v.z); v1[3]=f2bf(f2v.w);
    v1[4]=f2bf(f3.x); v1[5]=f2bf(f3.y); v1[6]=f2bf(f3.z); v1[7]=f2bf(f3.w);
    *(u16x8*)&As[arow][ahalf * 16]     = v0;
    *(u16x8*)&As[arow][ahalf * 16 + 8] = v1;
    *(u16x8*)&Bs[brow][bchunk * 8] = *(const u16x8*)(bptr + k0);
    __syncthreads();

    // frag layout: A row=lane&15, k=(lane>>4)*8+i ; B col=lane&15, k=(lane>>4)*8+i
    s16x8 af[2], bfr[4];
    #pragma unroll
    for (int mb = 0; mb < 2; ++mb)
      af[mb] = *(const s16x8*)&As[wave * 32 + mb * 16 + l16][lq * 8];
    #pragma unroll
    for (int nb = 0; nb < 4; ++nb)
      bfr[nb] = *(const s16x8*)&Bs[nb * 16 + l16][lq * 8];
    #pragma unroll
    for (int mb = 0; mb < 2; ++mb)
      #pragma unroll
      for (int nb = 0; nb < 4; ++nb)
        acc[mb][nb] = __builtin_amdgcn_mfma_f32_16x16x32_bf16(af[mb], bfr[nb], acc[mb][nb], 0, 0, 0);
    __syncthreads();
  }

  // C/D layout: col = lane&15, row = (lane>>4)*4 + reg  [measured m89/m91]
  #pragma unroll
  for (int mb = 0; mb < 2; ++mb) {
    const int rbase = row0 + wave * 32 + mb * 16 + lq * 4;
    #pragma unroll
    for (int r = 0; r < 4; ++r) {
      const int row = rbase + r;
      if (row < M) {
        #pragma unroll
        for (int nb = 0; nb < 4; ++nb) {
          const int col = col0 + nb * 16 + l16;
          float v = acc[mb][nb][r];
          if (bias) v += bias[col];
          C[(size_t)row * Ncols + col] = v;
        }
      }
    }
  }
}

// ---------------- conv1 edge kernels (4 heads x 64 ch), H1 = [N][512] = [H1l|H1r] ----
__global__ __launch_bounds__(256) void edge_score_h4(
    const float* __restrict__ H1, const void* __restrict__ ei, const int* __restrict__ flag,
    const float* __restrict__ att, float* __restrict__ e1,
    unsigned* __restrict__ emax)
{
  const int eidx = blockIdx.x * 4 + (threadIdx.x >> 6);
  if (eidx >= ETOT) return;
  const int lane = threadIdx.x & 63;
  int src, dst;
  load_edge(ei, *flag, eidx, src, dst);
  const float* xl = H1 + (size_t)src * 512;
  const float* xr = H1 + (size_t)dst * 512 + 256;
  float p0, p1, p2, p3;
  {
    float m;
    m = xl[lane]       + xr[lane];       m = m > 0.f ? m : 0.2f * m; p0 = m * att[lane];
    m = xl[64 + lane]  + xr[64 + lane];  m = m > 0.f ? m : 0.2f * m; p1 = m * att[64 + lane];
    m = xl[128 + lane] + xr[128 + lane]; m = m > 0.f ? m : 0.2f * m; p2 = m * att[128 + lane];
    m = xl[192 + lane] + xr[192 + lane]; m = m > 0.f ? m : 0.2f * m; p3 = m * att[192 + lane];
  }
  #pragma unroll
  for (int off = 32; off > 0; off >>= 1) {
    p0 += __shfl_xor(p0, off);
    p1 += __shfl_xor(p1, off);
    p2 += __shfl_xor(p2, off);
    p3 += __shfl_xor(p3, off);
  }
  if (lane < 4) {
    float pv = (lane == 0) ? p0 : (lane == 1) ? p1 : (lane == 2) ? p2 : p3;
    e1[(size_t)eidx * 4 + lane] = pv;
    atomicMax(&emax[dst * 4 + lane], fenc(pv));
  }
}

__global__ __launch_bounds__(256) void edge_alpha_h4(
    const void* __restrict__ ei, const int* __restrict__ flag, float* __restrict__ e1,
    const unsigned* __restrict__ emax, float* __restrict__ den)
{
  const int idx = blockIdx.x * 256 + threadIdx.x;
  if (idx >= ETOT * 4) return;
  const int eidx = idx >> 2, h = idx & 3;
  int src, dst;
  load_edge(ei, *flag, eidx, src, dst);
  const float a = __expf(e1[idx] - fdec(emax[dst * 4 + h]));
  e1[idx] = a;
  atomicAdd(&den[dst * 4 + h], a);
}

__global__ __launch_bounds__(256) void edge_aggr_h4(
    const float* __restrict__ H1, const void* __restrict__ ei, const int* __restrict__ flag,
    const float* __restrict__ e1, const float* __restrict__ den,
    float* __restrict__ agg)
{
  const int eidx = blockIdx.x * 4 + (threadIdx.x >> 6);
  if (eidx >= ETOT) return;
  const int lane = threadIdx.x & 63;
  int src, dst;
  load_edge(ei, *flag, eidx, src, dst);
  const float* xl = H1 + (size_t)src * 512;
  float* ao = agg + (size_t)dst * 256;
  #pragma unroll
  for (int h = 0; h < 4; ++h) {
    const float al = e1[(size_t)eidx * 4 + h] / den[dst * 4 + h];
    atomicAdd(&ao[h * 64 + lane], al * xl[h * 64 + lane]);
  }
}

// ---------------- conv2 edge kernels (1 head x 128 ch), H2 = [N][256] = [H2l|H2r] ----
__global__ __launch_bounds__(256) void edge_score_h1(
    const float* __restrict__ H2, const void* __restrict__ ei, const int* __restrict__ flag,
    const float* __restrict__ att, float* __restrict__ e2,
    unsigned* __restrict__ emax)
{
  const int eidx = blockIdx.x * 4 + (threadIdx.x >> 6);
  if (eidx >= ETOT) return;
  const int lane = threadIdx.x & 63;
  int src, dst;
  load_edge(ei, *flag, eidx, src, dst);
  const float* xl = H2 + (size_t)src * 256;
  const float* xr = H2 + (size_t)dst * 256 + 128;
  float m0 = xl[lane] + xr[lane];
  m0 = m0 > 0.f ? m0 : 0.2f * m0;
  float m1 = xl[64 + lane] + xr[64 + lane];
  m1 = m1 > 0.f ? m1 : 0.2f * m1;
  float pv = m0 * att[lane] + m1 * att[64 + lane];
  #pragma unroll
  for (int off = 32; off > 0; off >>= 1) pv += __shfl_xor(pv, off);
  if (lane == 0) {
    e2[eidx] = pv;
    atomicMax(&emax[dst], fenc(pv));
  }
}

__global__ __launch_bounds__(256) void edge_alpha_h1(
    const void* __restrict__ ei, const int* __restrict__ flag, float* __restrict__ e2,
    const unsigned* __restrict__ emax, float* __restrict__ den)
{
  const int eidx = blockIdx.x * 256 + threadIdx.x;
  if (eidx >= ETOT) return;
  int src, dst;
  load_edge(ei, *flag, eidx, src, dst);
  const float a = __expf(e2[eidx] - fdec(emax[dst]));
  e2[eidx] = a;
  atomicAdd(&den[dst], a);
}

__global__ __launch_bounds__(256) void edge_aggr_h1(
    const float* __restrict__ H2, const void* __restrict__ ei, const int* __restrict__ flag,
    const float* __restrict__ e2, const float* __restrict__ den,
    float* __restrict__ agg)
{
  const int eidx = blockIdx.x * 4 + (threadIdx.x >> 6);
  if (eidx >= ETOT) return;
  const int lane = threadIdx.x & 63;
  int src, dst;
  load_edge(ei, *flag, eidx, src, dst);
  const float al = e2[eidx] / den[dst];
  const float* xl = H2 + (size_t)src * 256;
  float* ao = agg + (size_t)dst * 128;
  atomicAdd(&ao[lane],      al * xl[lane]);
  atomicAdd(&ao[64 + lane], al * xl[64 + lane]);
}

// ---------------- misc elementwise / BN ----------------
__global__ __launch_bounds__(256) void bias_act(
    float* __restrict__ x, const float* __restrict__ b, int n, int cmask, int do_relu)
{
  const int i = blockIdx.x * 256 + threadIdx.x;
  if (i >= n) return;
  float v = x[i] + b[i & cmask];
  x[i] = do_relu ? fmaxf(v, 0.f) : v;
}

// dst_bf16[n][k] = (n<halfN ? Wa[k][n] : Wb[k][n-halfN]) ; grid=(ceil(K/256), Ntot)
__global__ __launch_bounds__(256) void wt_cvt(
    const float* __restrict__ Wa, const float* __restrict__ Wb,
    unsigned short* __restrict__ dst, int K, int halfN)
{
  const int k = blockIdx.x * 256 + threadIdx.x;
  const int n = blockIdx.y;
  if (k >= K) return;
  const float v = (n < halfN) ? Wa[(size_t)k * halfN + n]
                              : Wb[(size_t)k * halfN + (n - halfN)];
  dst[(size_t)n * K + k] = f2bf(v);
}

#define SROWS 256
__global__ __launch_bounds__(256) void bn_stats(
    const float* __restrict__ t, float* __restrict__ sums, int M)
{
  const int tid = threadIdx.x;
  const int c = tid & 127, half = tid >> 7;
  const int r0 = blockIdx.x * SROWS;
  int rend = r0 + SROWS; if (rend > M) rend = M;
  float s = 0.f, q = 0.f;
  for (int r = r0 + half; r < rend; r += 2) {
    const float v = t[(size_t)r * 128 + c];
    s += v; q += v * v;
  }
  __shared__ float ls[256], lq[256];
  ls[tid] = s; lq[tid] = q;
  __syncthreads();
  if (tid < 128) {
    atomicAdd(&sums[c],       ls[tid] + ls[tid + 128]);
    atomicAdd(&sums[128 + c], lq[tid] + lq[tid + 128]);
  }
}

__global__ void bn_final(const float* __restrict__ sums, const float* __restrict__ gamma,
                         const float* __restrict__ beta, float* __restrict__ bnp, int M)
{
  const int c = threadIdx.x;
  if (c < 128) {
    const float mu  = sums[c] / (float)M;
    const float var = sums[128 + c] / (float)M - mu * mu;
    const float sc  = gamma[c] * rsqrtf(var + 1e-5f);
    bnp[c] = sc;
    bnp[128 + c] = beta[c] - mu * sc;
  }
}

__global__ __launch_bounds__(256) void bn_apply(
    const float* __restrict__ t, const float* __restrict__ bnp,
    float* __restrict__ y, int n)
{
  const int i = blockIdx.x * 256 + threadIdx.x;
  if (i >= n) return;
  const int c = i & 127;
  y[i] = fmaxf(t[i] * bnp[c] + bnp[128 + c], 0.f);
}

// ---------------- launch ----------------
extern "C" void kernel_launch(void* const* d_in, const int* in_sizes, int n_in,
                              void* d_out, int out_size, void* d_ws, size_t ws_size,
                              hipStream_t stream)
{
  (void)in_sizes; (void)n_in; (void)out_size; (void)ws_size;
  const float* x     = (const float*)d_in[0];
  const void*  ei    = (const void*)d_in[1];   // int32 or int64 — detected on device
  const float* W1l   = (const float*)d_in[2];
  const float* W1r   = (const float*)d_in[3];
  const float* att1  = (const float*)d_in[4];
  const float* b1    = (const float*)d_in[5];
  const float* W2l   = (const float*)d_in[6];
  const float* W2r   = (const float*)d_in[7];
  const float* att2  = (const float*)d_in[8];
  const float* b2    = (const float*)d_in[9];
  const float* pw1   = (const float*)d_in[10];
  const float* pb1   = (const float*)d_in[11];
  const float* gamma = (const float*)d_in[12];
  const float* beta  = (const float*)d_in[13];
  const float* pw2   = (const float*)d_in[14];
  const float* pb2   = (const float*)d_in[15];

  // workspace layout (bytes); overlays: H2/t/y reuse H1's region, e2 reuses e1
  char* ws = (char*)d_ws;
  float*          H1    = (float*)(ws + 0);           // 50000*512*4 = 102,400,000
  float*          H2    = (float*)(ws + 0);           // 50000*256*4 (after H1 dead)
  float*          tbuf  = (float*)(ws + 51200000);    // 50000*128*4
  float*          ybuf  = (float*)(ws + 76800000);    // 50000*128*4
  float*          agg1  = (float*)(ws + 102400000);   // 50000*256*4 (becomes h1)
  float*          e1    = (float*)(ws + 153600000);   // 850000*4*4 (e2 reuses)
  unsigned*       emax  = (unsigned*)(ws + 167200000);// 50000*4*4
  float*          den   = (float*)(ws + 168000000);   // 50000*4*4
  float*          agg2  = (float*)(ws + 168800000);   // 50000*128*4 (becomes h2)
  unsigned short* WT1   = (unsigned short*)(ws + 194400000); // 512*2048*2
  unsigned short* WT2   = (unsigned short*)(ws + 196497152); // 256*256*2
  unsigned short* PT1   = (unsigned short*)(ws + 196628224); // 128*128*2
  unsigned short* PT2   = (unsigned short*)(ws + 196660992); // 128*128*2
  float*          bnsum = (float*)(ws + 196693760);   // 256*4
  float*          bnp   = (float*)(ws + 196694784);   // 256*4
  int*            eflag = (int*)(ws + 196695808);     // 4

  hipMemsetAsync(agg1, 0, 51200000, stream);
  hipMemsetAsync(agg2, 0, 25600000, stream);
  hipMemsetAsync(emax, 0, 800000, stream);   // 0 == encoded "below all floats"
  hipMemsetAsync(den,  0, 800000, stream);
  hipMemsetAsync(bnsum, 0, 1024, stream);

  detect_i64<<<1, 64, 0, stream>>>(ei, eflag);
  wt_cvt<<<dim3(8, 512), 256, 0, stream>>>(W1l, W1r, WT1, 2048, 256);
  wt_cvt<<<dim3(1, 256), 256, 0, stream>>>(W2l, W2r, WT2, 256, 128);
  wt_cvt<<<dim3(1, 128), 256, 0, stream>>>(pw1, pw1, PT1, 128, 128);
  wt_cvt<<<dim3(1, 128), 256, 0, stream>>>(pw2, pw2, PT2, 128, 128);

  // conv1: H1 = x @ [W1l|W1r]
  gemm_kernel<<<dim3(8, 391), 256, 0, stream>>>(x, WT1, H1, nullptr, NN, 2048, 512);

  const int eb = (ETOT + 3) / 4;
  edge_score_h4<<<eb, 256, 0, stream>>>(H1, ei, eflag, att1, e1, emax);
  edge_alpha_h4<<<(ETOT * 4 + 255) / 256, 256, 0, stream>>>(ei, eflag, e1, emax, den);
  edge_aggr_h4<<<eb, 256, 0, stream>>>(H1, ei, eflag, e1, den, agg1);
  bias_act<<<(NN * 256 + 255) / 256, 256, 0, stream>>>(agg1, b1, NN * 256, 255, 1);

  // conv2: H2 = h1 @ [W2l|W2r]
  gemm_kernel<<<dim3(4, 391), 256, 0, stream>>>(agg1, WT2, H2, nullptr, NN, 256, 256);

  hipMemsetAsync(emax, 0, 200000, stream);   // re-init for head-1 layer
  hipMemsetAsync(den,  0, 200000, stream);

  edge_score_h1<<<eb, 256, 0, stream>>>(H2, ei, eflag, att2, e1, emax);
  edge_alpha_h1<<<(ETOT + 255) / 256, 256, 0, stream>>>(ei, eflag, e1, emax, den);
  edge_aggr_h1<<<eb, 256, 0, stream>>>(H2, ei, eflag, e1, den, agg2);
  bias_act<<<(NN * 128 + 255) / 256, 256, 0, stream>>>(agg2, b2, NN * 128, 127, 0);

  // projection head
  gemm_kernel<<<dim3(2, 391), 256, 0, stream>>>(agg2, PT1, tbuf, pb1, NN, 128, 128);
  bn_stats<<<(NN + SROWS - 1) / SROWS, 256, 0, stream>>>(tbuf, bnsum, NN);
  bn_final<<<1, 128, 0, stream>>>(bnsum, gamma, beta, bnp, NN);
  bn_apply<<<(NN * 128 + 255) / 256, 256, 0, stream>>>(tbuf, bnp, ybuf, NN * 128);

  // final linear -> fp32 output (reference output dtype is float32)
  gemm_kernel<<<dim3(2, 391), 256, 0, stream>>>(ybuf, PT2, (float*)d_out, pb2, NN, 128, 128);
}

// Round 3
// 1117.918 us; speedup vs baseline: 1.9487x; 1.9487x over previous
//
#include <hip/hip_runtime.h>
#include <hip/hip_bf16.h>
#include <cstdint>
#include <cstddef>

#define NN 50000
#define NE 800000
#define ETOT (NN + NE)   // 850000 edges incl. self loops

typedef float f32x4 __attribute__((ext_vector_type(4)));
typedef short s16x8 __attribute__((ext_vector_type(8)));
typedef unsigned short u16x8 __attribute__((ext_vector_type(8)));

__device__ __forceinline__ unsigned short f2bf(float f) {
  unsigned u = __float_as_uint(f);
  u += 0x7FFFu + ((u >> 16) & 1u);   // round-to-nearest-even
  return (unsigned short)(u >> 16);
}

// edge_index may arrive as int32 or int64 (reference uses jnp.int64; harness may
// or may not downcast). A detect kernel writes flag=1 if the buffer is int64.
__global__ void detect_i64(const void* __restrict__ ei, int* __restrict__ flag) {
  const long long v = ((const long long*)ei)[threadIdx.x];
  const bool ok = (v >= 0 && v < NN);
  const unsigned long long m = __ballot(ok);
  if (threadIdx.x == 0) *flag = (m == ~0ULL) ? 1 : 0;
}

__device__ __forceinline__ void load_edge(const void* __restrict__ ei, int is64,
                                          int eidx, int& src, int& dst) {
  if (eidx >= NE) { src = dst = eidx - NE; return; }   // self loops appended
  if (is64) {
    src = (int)((const long long*)ei)[eidx];
    dst = (int)((const long long*)ei)[NE + eidx];
  } else {
    src = ((const int*)ei)[eidx];
    dst = ((const int*)ei)[NE + eidx];
  }
}

// ---------------- CSR build (by dst), shared by both conv layers ----------------
__global__ __launch_bounds__(256) void csr_hist(
    const void* __restrict__ ei, const int* __restrict__ flag, int* __restrict__ cnt)
{
  const int e = blockIdx.x * 256 + threadIdx.x;
  if (e >= ETOT) return;
  int src, dst;
  load_edge(ei, *flag, e, src, dst);
  atomicAdd(&cnt[dst], 1);
}

__global__ __launch_bounds__(1024) void csr_scan(
    const int* __restrict__ cnt, int* __restrict__ rowptr)
{
  __shared__ int ls[1024];
  const int tid = threadIdx.x;
  int run = 0;
  if (tid == 0) rowptr[0] = 0;
  for (int base = 0; base < NN; base += 1024) {
    int v = (base + tid < NN) ? cnt[base + tid] : 0;
    ls[tid] = v;
    __syncthreads();
    #pragma unroll
    for (int off = 1; off < 1024; off <<= 1) {
      int t = (tid >= off) ? ls[tid - off] : 0;
      __syncthreads();
      ls[tid] += t;
      __syncthreads();
    }
    if (base + tid < NN) rowptr[base + tid + 1] = run + ls[tid];
    run += ls[1023];
    __syncthreads();
  }
}

__global__ __launch_bounds__(256) void csr_scatter(
    const void* __restrict__ ei, const int* __restrict__ flag,
    const int* __restrict__ rowptr, int* __restrict__ cur, int* __restrict__ colv)
{
  const int e = blockIdx.x * 256 + threadIdx.x;
  if (e >= ETOT) return;
  int src, dst;
  load_edge(ei, *flag, e, src, dst);
  const int pos = atomicAdd(&cur[dst], 1);
  colv[rowptr[dst] + pos] = src;
}

// ---------------- GEMM: C[M][Ncols] = A_f32[M][K] @ BT_bf16[Ncols][K]^T (+bias) ----
#define BM 128
#define BN 64
#define BK 32
#define LDK 40   // 32 + 8 shorts pad

__global__ __launch_bounds__(256) void gemm_kernel(
    const float* __restrict__ A, const unsigned short* __restrict__ BT,
    float* __restrict__ C, const float* __restrict__ bias,
    int M, int K, int Ncols)
{
  __shared__ unsigned short As[BM][LDK];
  __shared__ unsigned short Bs[BN][LDK];
  const int tid  = threadIdx.x;
  const int wave = tid >> 6;
  const int lane = tid & 63;
  const int l16  = lane & 15;
  const int lq   = lane >> 4;
  const int col0 = blockIdx.x * BN;
  const int row0 = blockIdx.y * BM;

  const int arow  = tid >> 1;
  const int ahalf = tid & 1;
  int ag = row0 + arow; if (ag > M - 1) ag = M - 1;
  const float* aptr = A + (size_t)ag * K + ahalf * 16;
  const int brow   = tid >> 2;
  const int bchunk = tid & 3;
  const unsigned short* bptr = BT + (size_t)(col0 + brow) * K + bchunk * 8;

  f32x4 acc[2][4];
  #pragma unroll
  for (int i = 0; i < 2; ++i)
    #pragma unroll
    for (int j = 0; j < 4; ++j)
      #pragma unroll
      for (int r = 0; r < 4; ++r) acc[i][j][r] = 0.f;

  for (int k0 = 0; k0 < K; k0 += BK) {
    const float4* ap = (const float4*)(aptr + k0);
    float4 f0 = ap[0], f1 = ap[1], f2v = ap[2], f3 = ap[3];
    u16x8 v0, v1;
    v0[0]=f2bf(f0.x); v0[1]=f2bf(f0.y); v0[2]=f2bf(f0.z); v0[3]=f2bf(f0.w);
    v0[4]=f2bf(f1.x); v0[5]=f2bf(f1.y); v0[6]=f2bf(f1.z); v0[7]=f2bf(f1.w);
    v1[0]=f2bf(f2v.x); v1[1]=f2bf(f2v.y); v1[2]=f2bf(f2v.z); v1[3]=f2bf(f2v.w);
    v1[4]=f2bf(f3.x); v1[5]=f2bf(f3.y); v1[6]=f2bf(f3.z); v1[7]=f2bf(f3.w);
    *(u16x8*)&As[arow][ahalf * 16]     = v0;
    *(u16x8*)&As[arow][ahalf * 16 + 8] = v1;
    *(u16x8*)&Bs[brow][bchunk * 8] = *(const u16x8*)(bptr + k0);
    __syncthreads();

    s16x8 af[2], bfr[4];
    #pragma unroll
    for (int mb = 0; mb < 2; ++mb)
      af[mb] = *(const s16x8*)&As[wave * 32 + mb * 16 + l16][lq * 8];
    #pragma unroll
    for (int nb = 0; nb < 4; ++nb)
      bfr[nb] = *(const s16x8*)&Bs[nb * 16 + l16][lq * 8];
    #pragma unroll
    for (int mb = 0; mb < 2; ++mb)
      #pragma unroll
      for (int nb = 0; nb < 4; ++nb)
        acc[mb][nb] = __builtin_amdgcn_mfma_f32_16x16x32_bf16(af[mb], bfr[nb], acc[mb][nb], 0, 0, 0);
    __syncthreads();
  }

  // C/D layout: col = lane&15, row = (lane>>4)*4 + reg  [measured m89/m91]
  #pragma unroll
  for (int mb = 0; mb < 2; ++mb) {
    const int rbase = row0 + wave * 32 + mb * 16 + lq * 4;
    #pragma unroll
    for (int r = 0; r < 4; ++r) {
      const int row = rbase + r;
      if (row < M) {
        #pragma unroll
        for (int nb = 0; nb < 4; ++nb) {
          const int col = col0 + nb * 16 + l16;
          float v = acc[mb][nb][r];
          if (bias) v += bias[col];
          C[(size_t)row * Ncols + col] = v;
        }
      }
    }
  }
}

// ---------------- fused per-node GATv2 (score + online softmax + aggregate) ------
// conv1: 4 heads x 64ch. H1=[N][512]=[xl|xr]. One wave per dst node.
__global__ __launch_bounds__(256) void node_conv1(
    const float* __restrict__ H1, const int* __restrict__ rowptr,
    const int* __restrict__ colv, const float* __restrict__ att,
    const float* __restrict__ bias, float* __restrict__ out)
{
  const int node = blockIdx.x * 4 + (threadIdx.x >> 6);
  if (node >= NN) return;
  const int lane = threadIdx.x & 63;
  float xr[4], at[4];
  #pragma unroll
  for (int h = 0; h < 4; ++h) {
    xr[h] = H1[(size_t)node * 512 + 256 + h * 64 + lane];
    at[h] = att[h * 64 + lane];
  }
  float m[4], s[4], acc[4];
  #pragma unroll
  for (int h = 0; h < 4; ++h) { m[h] = -1e30f; s[h] = 0.f; acc[h] = 0.f; }

  const int beg = rowptr[node], end = rowptr[node + 1];
  int src = colv[beg];
  float xl[4];
  #pragma unroll
  for (int h = 0; h < 4; ++h) xl[h] = H1[(size_t)src * 512 + h * 64 + lane];

  for (int i = beg; i < end; ++i) {
    float xln[4] = {0.f, 0.f, 0.f, 0.f};
    if (i + 1 < end) {                      // prefetch next edge's gather
      const int srcn = colv[i + 1];
      #pragma unroll
      for (int h = 0; h < 4; ++h) xln[h] = H1[(size_t)srcn * 512 + h * 64 + lane];
    }
    float e[4];
    #pragma unroll
    for (int h = 0; h < 4; ++h) {
      float mm = xl[h] + xr[h];
      mm = mm > 0.f ? mm : 0.2f * mm;
      e[h] = mm * at[h];
    }
    #pragma unroll
    for (int off = 32; off > 0; off >>= 1) {
      #pragma unroll
      for (int h = 0; h < 4; ++h) e[h] += __shfl_xor(e[h], off);
    }
    #pragma unroll
    for (int h = 0; h < 4; ++h) {
      const float mn = fmaxf(m[h], e[h]);
      const float sc = __expf(m[h] - mn);
      const float w  = __expf(e[h] - mn);
      s[h]   = s[h] * sc + w;
      acc[h] = acc[h] * sc + w * xl[h];
      m[h]   = mn;
    }
    #pragma unroll
    for (int h = 0; h < 4; ++h) xl[h] = xln[h];
  }
  #pragma unroll
  for (int h = 0; h < 4; ++h)
    out[(size_t)node * 256 + h * 64 + lane] = fmaxf(acc[h] / s[h] + bias[h * 64 + lane], 0.f);
}

// conv2: 1 head x 128ch. H2=[N][256]=[xl|xr]. One wave per dst node.
__global__ __launch_bounds__(256) void node_conv2(
    const float* __restrict__ H2, const int* __restrict__ rowptr,
    const int* __restrict__ colv, const float* __restrict__ att,
    const float* __restrict__ bias, float* __restrict__ out)
{
  const int node = blockIdx.x * 4 + (threadIdx.x >> 6);
  if (node >= NN) return;
  const int lane = threadIdx.x & 63;
  const float xr0 = H2[(size_t)node * 256 + 128 + lane];
  const float xr1 = H2[(size_t)node * 256 + 192 + lane];
  const float a0 = att[lane], a1 = att[64 + lane];
  float m = -1e30f, s = 0.f, acc0 = 0.f, acc1 = 0.f;

  const int beg = rowptr[node], end = rowptr[node + 1];
  int src = colv[beg];
  float xl0 = H2[(size_t)src * 256 + lane];
  float xl1 = H2[(size_t)src * 256 + 64 + lane];

  for (int i = beg; i < end; ++i) {
    float xn0 = 0.f, xn1 = 0.f;
    if (i + 1 < end) {
      const int srcn = colv[i + 1];
      xn0 = H2[(size_t)srcn * 256 + lane];
      xn1 = H2[(size_t)srcn * 256 + 64 + lane];
    }
    float m0 = xl0 + xr0; m0 = m0 > 0.f ? m0 : 0.2f * m0;
    float m1 = xl1 + xr1; m1 = m1 > 0.f ? m1 : 0.2f * m1;
    float e = m0 * a0 + m1 * a1;
    #pragma unroll
    for (int off = 32; off > 0; off >>= 1) e += __shfl_xor(e, off);
    const float mn = fmaxf(m, e);
    const float sc = __expf(m - mn);
    const float w  = __expf(e - mn);
    s = s * sc + w;
    acc0 = acc0 * sc + w * xl0;
    acc1 = acc1 * sc + w * xl1;
    m = mn;
    xl0 = xn0; xl1 = xn1;
  }
  out[(size_t)node * 128 + lane]      = acc0 / s + bias[lane];
  out[(size_t)node * 128 + 64 + lane] = acc1 / s + bias[64 + lane];
}

// ---------------- misc ----------------
// dst_bf16[n][k] = (n<halfN ? Wa[k][n] : Wb[k][n-halfN])
__global__ __launch_bounds__(256) void wt_cvt(
    const float* __restrict__ Wa, const float* __restrict__ Wb,
    unsigned short* __restrict__ dst, int K, int halfN)
{
  const int k = blockIdx.x * 256 + threadIdx.x;
  const int n = blockIdx.y;
  if (k >= K) return;
  const float v = (n < halfN) ? Wa[(size_t)k * halfN + n]
                              : Wb[(size_t)k * halfN + (n - halfN)];
  dst[(size_t)n * K + k] = f2bf(v);
}

#define SROWS 256
__global__ __launch_bounds__(256) void bn_stats(
    const float* __restrict__ t, float* __restrict__ sums, int M)
{
  const int tid = threadIdx.x;
  const int c = tid & 127, half = tid >> 7;
  const int r0 = blockIdx.x * SROWS;
  int rend = r0 + SROWS; if (rend > M) rend = M;
  float s = 0.f, q = 0.f;
  for (int r = r0 + half; r < rend; r += 2) {
    const float v = t[(size_t)r * 128 + c];
    s += v; q += v * v;
  }
  __shared__ float ls[256], lq[256];
  ls[tid] = s; lq[tid] = q;
  __syncthreads();
  if (tid < 128) {
    atomicAdd(&sums[c],       ls[tid] + ls[tid + 128]);
    atomicAdd(&sums[128 + c], lq[tid] + lq[tid + 128]);
  }
}

__global__ void bn_final(const float* __restrict__ sums, const float* __restrict__ gamma,
                         const float* __restrict__ beta, float* __restrict__ bnp, int M)
{
  const int c = threadIdx.x;
  if (c < 128) {
    const float mu  = sums[c] / (float)M;
    const float var = sums[128 + c] / (float)M - mu * mu;
    const float sc  = gamma[c] * rsqrtf(var + 1e-5f);
    bnp[c] = sc;
    bnp[128 + c] = beta[c] - mu * sc;
  }
}

__global__ __launch_bounds__(256) void bn_apply(
    const float* __restrict__ t, const float* __restrict__ bnp,
    float* __restrict__ y, int n)
{
  const int i = blockIdx.x * 256 + threadIdx.x;
  if (i >= n) return;
  const int c = i & 127;
  y[i] = fmaxf(t[i] * bnp[c] + bnp[128 + c], 0.f);
}

// ---------------- launch ----------------
extern "C" void kernel_launch(void* const* d_in, const int* in_sizes, int n_in,
                              void* d_out, int out_size, void* d_ws, size_t ws_size,
                              hipStream_t stream)
{
  (void)in_sizes; (void)n_in; (void)out_size; (void)ws_size;
  const float* x     = (const float*)d_in[0];
  const void*  ei    = (const void*)d_in[1];   // int32 or int64 — detected on device
  const float* W1l   = (const float*)d_in[2];
  const float* W1r   = (const float*)d_in[3];
  const float* att1  = (const float*)d_in[4];
  const float* b1    = (const float*)d_in[5];
  const float* W2l   = (const float*)d_in[6];
  const float* W2r   = (const float*)d_in[7];
  const float* att2  = (const float*)d_in[8];
  const float* b2    = (const float*)d_in[9];
  const float* pw1   = (const float*)d_in[10];
  const float* pb1   = (const float*)d_in[11];
  const float* gamma = (const float*)d_in[12];
  const float* beta  = (const float*)d_in[13];
  const float* pw2   = (const float*)d_in[14];
  const float* pb2   = (const float*)d_in[15];

  // workspace layout (bytes) with overlays:
  //  [0,102.4M)      H1 [N][512] ; later H2 [N][256] at 0 (H1 dead after node_conv1)
  //  [51.2M,76.8M)   h2 [N][128] (inside dead H1)
  //  [76.8M,102.4M)  tbuf [N][128]
  //  [102.4M,153.6M) h1 [N][256] ; later ybuf at 102.4M (h1 dead after gemm2)
  char* ws = (char*)d_ws;
  float*          H1     = (float*)(ws + 0);
  float*          H2     = (float*)(ws + 0);
  float*          h2buf  = (float*)(ws + 51200000);
  float*          tbuf   = (float*)(ws + 76800000);
  float*          h1buf  = (float*)(ws + 102400000);
  float*          ybuf   = (float*)(ws + 102400000);
  int*            rowptr = (int*)(ws + 153600000);   // 50001*4
  int*            cnt    = (int*)(ws + 153800192);   // 50000*4
  int*            colv   = (int*)(ws + 154000384);   // 850000*4
  unsigned short* WT1    = (unsigned short*)(ws + 157400384); // 512*2048*2
  unsigned short* WT2    = (unsigned short*)(ws + 159497536); // 256*256*2
  unsigned short* PT1    = (unsigned short*)(ws + 159628608); // 128*128*2
  unsigned short* PT2    = (unsigned short*)(ws + 159661376); // 128*128*2
  float*          bnsum  = (float*)(ws + 159694144);  // 256*4
  float*          bnp    = (float*)(ws + 159695168);  // 256*4
  int*            eflag  = (int*)(ws + 159696192);    // 4

  hipMemsetAsync(cnt, 0, 200000, stream);
  hipMemsetAsync(bnsum, 0, 1024, stream);

  detect_i64<<<1, 64, 0, stream>>>(ei, eflag);
  wt_cvt<<<dim3(8, 512), 256, 0, stream>>>(W1l, W1r, WT1, 2048, 256);
  wt_cvt<<<dim3(1, 256), 256, 0, stream>>>(W2l, W2r, WT2, 256, 128);
  wt_cvt<<<dim3(1, 128), 256, 0, stream>>>(pw1, pw1, PT1, 128, 128);
  wt_cvt<<<dim3(1, 128), 256, 0, stream>>>(pw2, pw2, PT2, 128, 128);

  // CSR by dst (shared by both conv layers)
  const int ebl = (ETOT + 255) / 256;
  csr_hist<<<ebl, 256, 0, stream>>>(ei, eflag, cnt);
  csr_scan<<<1, 1024, 0, stream>>>(cnt, rowptr);
  hipMemsetAsync(cnt, 0, 200000, stream);   // reuse as scatter cursor
  csr_scatter<<<ebl, 256, 0, stream>>>(ei, eflag, rowptr, cnt, colv);

  // conv1: H1 = x @ [W1l|W1r], then fused edge-softmax-aggregate (+b1, ReLU)
  gemm_kernel<<<dim3(8, 391), 256, 0, stream>>>(x, WT1, H1, nullptr, NN, 2048, 512);
  node_conv1<<<(NN + 3) / 4, 256, 0, stream>>>(H1, rowptr, colv, att1, b1, h1buf);

  // conv2: H2 = h1 @ [W2l|W2r], then fused aggregate (+b2)
  gemm_kernel<<<dim3(4, 391), 256, 0, stream>>>(h1buf, WT2, H2, nullptr, NN, 256, 256);
  node_conv2<<<(NN + 3) / 4, 256, 0, stream>>>(H2, rowptr, colv, att2, b2, h2buf);

  // projection head
  gemm_kernel<<<dim3(2, 391), 256, 0, stream>>>(h2buf, PT1, tbuf, pb1, NN, 128, 128);
  bn_stats<<<(NN + SROWS - 1) / SROWS, 256, 0, stream>>>(tbuf, bnsum, NN);
  bn_final<<<1, 128, 0, stream>>>(bnsum, gamma, beta, bnp, NN);
  bn_apply<<<(NN * 128 + 255) / 256, 256, 0, stream>>>(tbuf, bnp, ybuf, NN * 128);

  // final linear -> fp32 output
  gemm_kernel<<<dim3(2, 391), 256, 0, stream>>>(ybuf, PT2, (float*)d_out, pb2, NN, 128, 128);
}

// Round 4
// 756.522 us; speedup vs baseline: 2.8796x; 1.4777x over previous
//
#include <hip/hip_runtime.h>
#include <hip/hip_bf16.h>
#include <cstdint>
#include <cstddef>

#define NN 50000
#define NE 800000
#define ETOT (NN + NE)   // 850000 edges incl. self loops

typedef float f32x4 __attribute__((ext_vector_type(4)));
typedef short s16x8 __attribute__((ext_vector_type(8)));

__device__ __forceinline__ unsigned short f2bf(float f) {
  unsigned u = __float_as_uint(f);
  u += 0x7FFFu + ((u >> 16) & 1u);   // RNE
  return (unsigned short)(u >> 16);
}
__device__ __forceinline__ float bf2f(unsigned short u) {
  return __uint_as_float(((unsigned)u) << 16);
}
__device__ __forceinline__ unsigned cvtpk(float lo, float hi) {  // 2xf32 -> packed bf16 (RNE)
  unsigned r;
  asm("v_cvt_pk_bf16_f32 %0, %1, %2" : "=v"(r) : "v"(lo), "v"(hi));
  return r;
}
typedef const __attribute__((address_space(1))) void* gas_t;
typedef __attribute__((address_space(3))) void* las_t;
__device__ __forceinline__ void gload_lds16(const void* g, void* l) {
  __builtin_amdgcn_global_load_lds((gas_t)g, (las_t)l, 16, 0, 0);
}

// edge_index may arrive as int32 or int64; detect on device (deterministic input).
__global__ void detect_i64(const void* __restrict__ ei, int* __restrict__ flag) {
  const long long v = ((const long long*)ei)[threadIdx.x];
  const bool ok = (v >= 0 && v < NN);
  const unsigned long long m = __ballot(ok);
  if (threadIdx.x == 0) *flag = (m == ~0ULL) ? 1 : 0;
}
__device__ __forceinline__ void load_edge(const void* __restrict__ ei, int is64,
                                          int eidx, int& src, int& dst) {
  if (eidx >= NE) { src = dst = eidx - NE; return; }
  if (is64) {
    src = (int)((const long long*)ei)[eidx];
    dst = (int)((const long long*)ei)[NE + eidx];
  } else {
    src = ((const int*)ei)[eidx];
    dst = ((const int*)ei)[NE + eidx];
  }
}

// ---------------- CSR build (by dst) ----------------
__global__ __launch_bounds__(256) void csr_hist(
    const void* __restrict__ ei, const int* __restrict__ flag, int* __restrict__ cnt)
{
  const int e = blockIdx.x * 256 + threadIdx.x;
  if (e >= ETOT) return;
  int src, dst;
  load_edge(ei, *flag, e, src, dst);
  atomicAdd(&cnt[dst], 1);
}

__global__ __launch_bounds__(1024) void csr_scan(
    const int* __restrict__ cnt, int* __restrict__ rowptr)
{
  __shared__ int ls[1024];
  const int tid = threadIdx.x;
  int run = 0;
  if (tid == 0) rowptr[0] = 0;
  for (int base = 0; base < NN; base += 1024) {
    int v = (base + tid < NN) ? cnt[base + tid] : 0;
    ls[tid] = v;
    __syncthreads();
    #pragma unroll
    for (int off = 1; off < 1024; off <<= 1) {
      int t = (tid >= off) ? ls[tid - off] : 0;
      __syncthreads();
      ls[tid] += t;
      __syncthreads();
    }
    if (base + tid < NN) rowptr[base + tid + 1] = run + ls[tid];
    run += ls[1023];
    __syncthreads();
  }
}

__global__ __launch_bounds__(256) void csr_scatter(
    const void* __restrict__ ei, const int* __restrict__ flag,
    const int* __restrict__ rowptr, int* __restrict__ cur, int* __restrict__ colv)
{
  const int e = blockIdx.x * 256 + threadIdx.x;
  if (e >= ETOT) return;
  int src, dst;
  load_edge(ei, *flag, e, src, dst);
  const int pos = atomicAdd(&cur[dst], 1);
  colv[rowptr[dst] + pos] = src;
}

// ---------------- GEMM (m97 structure): C[M][Nc] = A[M][K] @ BT[Nc][K]^T -------
// 128x128 tile, 4 waves (2x2), 4x4 16x16x32 frags/wave, BK=32, linear LDS,
// global_load_lds(16B) for bf16 operands; fp32-A path converts via v_cvt_pk_bf16.
template<bool ABF16>
__global__ __launch_bounds__(256) void gemm_t(
    const void* __restrict__ Av, const unsigned short* __restrict__ BT,
    void* __restrict__ Cv, const float* __restrict__ bias,
    int M, int K, int Ncols, int out_bf16, int nbx, int nwg)
{
  __shared__ unsigned short As[128 * 32];
  __shared__ unsigned short Bs[128 * 32];

  int bid = blockIdx.x;
  {  // bijective XCD-chunked swizzle (m204): contiguous row-panels per XCD
    const int q = nwg >> 3, r = nwg & 7;
    const int xcd = bid & 7, idx = bid >> 3;
    bid = (xcd < r ? xcd * (q + 1) : r * (q + 1) + (xcd - r) * q) + idx;
  }
  const int bx = bid % nbx, by = bid / nbx;
  const int row0 = by * 128, col0 = bx * 128;
  const int tid = threadIdx.x, wave = tid >> 6, lane = tid & 63;
  const int l16 = lane & 15, lq = lane >> 4;
  const int wr = wave >> 1, wc = wave & 1;

  // staging: chunk c in [0,512) = (row=c>>2, part=c&3, 8 ushorts); thread: {tid, tid+256}
  const int c0 = tid, c1 = tid + 256;
  int ar0 = row0 + (c0 >> 2); if (ar0 >= M) ar0 = M - 1;
  int ar1 = row0 + (c1 >> 2); if (ar1 >= M) ar1 = M - 1;
  const int ap0 = (c0 & 3) * 8, ap1 = (c1 & 3) * 8;
  const int br0 = col0 + (c0 >> 2), br1 = col0 + (c1 >> 2);
  const unsigned short* Ab = (const unsigned short*)Av;
  const float*          Af = (const float*)Av;

  f32x4 acc[4][4];
  #pragma unroll
  for (int i = 0; i < 4; ++i)
    #pragma unroll
    for (int j = 0; j < 4; ++j)
      #pragma unroll
      for (int r = 0; r < 4; ++r) acc[i][j][r] = 0.f;

  for (int k0 = 0; k0 < K; k0 += 32) {
    if (ABF16) {
      gload_lds16(Ab + (size_t)ar0 * K + k0 + ap0, As + c0 * 8);
      gload_lds16(Ab + (size_t)ar1 * K + k0 + ap1, As + c1 * 8);
    } else {
      const float4 a0 = *(const float4*)(Af + (size_t)ar0 * K + k0 + ap0);
      const float4 a1 = *(const float4*)(Af + (size_t)ar0 * K + k0 + ap0 + 4);
      const float4 a2 = *(const float4*)(Af + (size_t)ar1 * K + k0 + ap1);
      const float4 a3 = *(const float4*)(Af + (size_t)ar1 * K + k0 + ap1 + 4);
      uint4 w0, w1;
      w0.x = cvtpk(a0.x, a0.y); w0.y = cvtpk(a0.z, a0.w);
      w0.z = cvtpk(a1.x, a1.y); w0.w = cvtpk(a1.z, a1.w);
      w1.x = cvtpk(a2.x, a2.y); w1.y = cvtpk(a2.z, a2.w);
      w1.z = cvtpk(a3.x, a3.y); w1.w = cvtpk(a3.z, a3.w);
      *(uint4*)&As[c0 * 8] = w0;
      *(uint4*)&As[c1 * 8] = w1;
    }
    gload_lds16(BT + (size_t)br0 * K + k0 + ap0, Bs + c0 * 8);
    gload_lds16(BT + (size_t)br1 * K + k0 + ap1, Bs + c1 * 8);
    __syncthreads();   // drains vmcnt (gload_lds) + lgkm (ds_write)

    s16x8 af[4], bf[4];
    #pragma unroll
    for (int f = 0; f < 4; ++f)
      af[f] = *(const s16x8*)&As[(wr * 64 + f * 16 + l16) * 32 + lq * 8];
    #pragma unroll
    for (int f = 0; f < 4; ++f)
      bf[f] = *(const s16x8*)&Bs[(wc * 64 + f * 16 + l16) * 32 + lq * 8];
    #pragma unroll
    for (int fm = 0; fm < 4; ++fm)
      #pragma unroll
      for (int fn = 0; fn < 4; ++fn)
        acc[fm][fn] = __builtin_amdgcn_mfma_f32_16x16x32_bf16(af[fm], bf[fn], acc[fm][fn], 0, 0, 0);
    __syncthreads();   // all reads done before next stage overwrites
  }

  float bv[4];
  #pragma unroll
  for (int fn = 0; fn < 4; ++fn)
    bv[fn] = bias ? bias[col0 + wc * 64 + fn * 16 + l16] : 0.f;

  // C/D layout: col = l16, row = lq*4 + r (verified m89/m91 + rounds 2-3)
  #pragma unroll
  for (int fm = 0; fm < 4; ++fm) {
    #pragma unroll
    for (int r = 0; r < 4; ++r) {
      const int row = row0 + wr * 64 + fm * 16 + lq * 4 + r;
      if (row < M) {
        #pragma unroll
        for (int fn = 0; fn < 4; ++fn) {
          const int col = col0 + wc * 64 + fn * 16 + l16;
          const float v = acc[fm][fn][r] + bv[fn];
          if (out_bf16) ((unsigned short*)Cv)[(size_t)row * Ncols + col] = f2bf(v);
          else          ((float*)Cv)[(size_t)row * Ncols + col] = v;
        }
      }
    }
  }
}

// ---------------- fused per-node GATv2 (online softmax + aggregate), bf16 I/O ----
// conv1: 4 heads x 64ch. H1=[N][512] bf16. Wave per node; lane = (head=lane>>4, 4ch).
__global__ __launch_bounds__(256) void node_conv1(
    const unsigned short* __restrict__ H1, const int* __restrict__ rowptr,
    const int* __restrict__ colv, const float* __restrict__ att,
    const float* __restrict__ b1, unsigned short* __restrict__ out)
{
  const int node = blockIdx.x * 4 + (threadIdx.x >> 6);
  if (node >= NN) return;
  const int lane = threadIdx.x & 63;
  const int base4 = lane * 4;   // == (lane>>4)*64 + (lane&15)*4
  float xr[4], at[4];
  {
    const ushort4 t = *(const ushort4*)&H1[(size_t)node * 512 + 256 + base4];
    xr[0] = bf2f(t.x); xr[1] = bf2f(t.y); xr[2] = bf2f(t.z); xr[3] = bf2f(t.w);
    at[0] = att[base4]; at[1] = att[base4 + 1]; at[2] = att[base4 + 2]; at[3] = att[base4 + 3];
  }
  float m = -1e30f, s = 0.f, a0 = 0.f, a1 = 0.f, a2 = 0.f, a3 = 0.f;
  const int beg = rowptr[node], end = rowptr[node + 1];
  ushort4 xs = *(const ushort4*)&H1[(size_t)colv[beg] * 512 + base4];
  for (int i = beg; i < end; ++i) {
    const int srcn = colv[(i + 1 < end) ? i + 1 : i];
    const ushort4 xn = *(const ushort4*)&H1[(size_t)srcn * 512 + base4];  // prefetch
    const float x0 = bf2f(xs.x), x1 = bf2f(xs.y), x2 = bf2f(xs.z), x3 = bf2f(xs.w);
    float mm, e = 0.f;
    mm = x0 + xr[0]; mm = mm > 0.f ? mm : 0.2f * mm; e += mm * at[0];
    mm = x1 + xr[1]; mm = mm > 0.f ? mm : 0.2f * mm; e += mm * at[1];
    mm = x2 + xr[2]; mm = mm > 0.f ? mm : 0.2f * mm; e += mm * at[2];
    mm = x3 + xr[3]; mm = mm > 0.f ? mm : 0.2f * mm; e += mm * at[3];
    e += __shfl_xor(e, 1); e += __shfl_xor(e, 2);
    e += __shfl_xor(e, 4); e += __shfl_xor(e, 8);   // 16-lane group = one head
    const float mn = fmaxf(m, e);
    const float sc = __expf(m - mn);
    const float w  = __expf(e - mn);
    s = s * sc + w;
    a0 = a0 * sc + w * x0; a1 = a1 * sc + w * x1;
    a2 = a2 * sc + w * x2; a3 = a3 * sc + w * x3;
    m = mn;
    xs = xn;
  }
  const float inv = 1.f / s;
  ushort4 o;
  o.x = f2bf(fmaxf(a0 * inv + b1[base4],     0.f));
  o.y = f2bf(fmaxf(a1 * inv + b1[base4 + 1], 0.f));
  o.z = f2bf(fmaxf(a2 * inv + b1[base4 + 2], 0.f));
  o.w = f2bf(fmaxf(a3 * inv + b1[base4 + 3], 0.f));
  *(ushort4*)&out[(size_t)node * 256 + base4] = o;
}

// conv2: 1 head x 128ch. H2=[N][256] bf16. Wave per node; lane = 2 channels.
__global__ __launch_bounds__(256) void node_conv2(
    const unsigned short* __restrict__ H2, const int* __restrict__ rowptr,
    const int* __restrict__ colv, const float* __restrict__ att,
    const float* __restrict__ b2, unsigned short* __restrict__ out)
{
  const int node = blockIdx.x * 4 + (threadIdx.x >> 6);
  if (node >= NN) return;
  const int lane = threadIdx.x & 63;
  const int c2 = lane * 2;
  float xr0, xr1, at0, at1;
  {
    const ushort2 t = *(const ushort2*)&H2[(size_t)node * 256 + 128 + c2];
    xr0 = bf2f(t.x); xr1 = bf2f(t.y);
    at0 = att[c2]; at1 = att[c2 + 1];
  }
  float m = -1e30f, s = 0.f, a0 = 0.f, a1 = 0.f;
  const int beg = rowptr[node], end = rowptr[node + 1];
  ushort2 xs = *(const ushort2*)&H2[(size_t)colv[beg] * 256 + c2];
  for (int i = beg; i < end; ++i) {
    const int srcn = colv[(i + 1 < end) ? i + 1 : i];
    const ushort2 xn = *(const ushort2*)&H2[(size_t)srcn * 256 + c2];
    const float x0 = bf2f(xs.x), x1 = bf2f(xs.y);
    float mm, e = 0.f;
    mm = x0 + xr0; mm = mm > 0.f ? mm : 0.2f * mm; e += mm * at0;
    mm = x1 + xr1; mm = mm > 0.f ? mm : 0.2f * mm; e += mm * at1;
    #pragma unroll
    for (int off = 32; off > 0; off >>= 1) e += __shfl_xor(e, off);
    const float mn = fmaxf(m, e);
    const float sc = __expf(m - mn);
    const float w  = __expf(e - mn);
    s = s * sc + w;
    a0 = a0 * sc + w * x0; a1 = a1 * sc + w * x1;
    m = mn;
    xs = xn;
  }
  const float inv = 1.f / s;
  ushort2 o;
  o.x = f2bf(a0 * inv + b2[c2]);
  o.y = f2bf(a1 * inv + b2[c2 + 1]);
  *(ushort2*)&out[(size_t)node * 128 + c2] = o;
}

// ---------------- misc ----------------
// dst_bf16[n][k] = (n<halfN ? Wa[k][n] : Wb[k][n-halfN])
__global__ __launch_bounds__(256) void wt_cvt(
    const float* __restrict__ Wa, const float* __restrict__ Wb,
    unsigned short* __restrict__ dst, int K, int halfN)
{
  const int k = blockIdx.x * 256 + threadIdx.x;
  const int n = blockIdx.y;
  if (k >= K) return;
  const float v = (n < halfN) ? Wa[(size_t)k * halfN + n]
                              : Wb[(size_t)k * halfN + (n - halfN)];
  dst[(size_t)n * K + k] = f2bf(v);
}

#define SROWS 256
__global__ __launch_bounds__(256) void bn_stats(
    const float* __restrict__ t, float* __restrict__ sums, int M)
{
  const int tid = threadIdx.x;
  const int c = tid & 127, half = tid >> 7;
  const int r0 = blockIdx.x * SROWS;
  int rend = r0 + SROWS; if (rend > M) rend = M;
  float s = 0.f, q = 0.f;
  for (int r = r0 + half; r < rend; r += 2) {
    const float v = t[(size_t)r * 128 + c];
    s += v; q += v * v;
  }
  __shared__ float ls[256], lq[256];
  ls[tid] = s; lq[tid] = q;
  __syncthreads();
  if (tid < 128) {
    atomicAdd(&sums[c],       ls[tid] + ls[tid + 128]);
    atomicAdd(&sums[128 + c], lq[tid] + lq[tid + 128]);
  }
}

__global__ void bn_final(const float* __restrict__ sums, const float* __restrict__ gamma,
                         const float* __restrict__ beta, float* __restrict__ bnp, int M)
{
  const int c = threadIdx.x;
  if (c < 128) {
    const float mu  = sums[c] / (float)M;
    const float var = sums[128 + c] / (float)M - mu * mu;
    const float sc  = gamma[c] * rsqrtf(var + 1e-5f);
    bnp[c] = sc;
    bnp[128 + c] = beta[c] - mu * sc;
  }
}

__global__ __launch_bounds__(256) void bn_apply(
    const float* __restrict__ t, const float* __restrict__ bnp,
    unsigned short* __restrict__ y, int n)
{
  const int i = blockIdx.x * 256 + threadIdx.x;
  if (i >= n) return;
  const int c = i & 127;
  y[i] = f2bf(fmaxf(t[i] * bnp[c] + bnp[128 + c], 0.f));
}

// ---------------- launch ----------------
extern "C" void kernel_launch(void* const* d_in, const int* in_sizes, int n_in,
                              void* d_out, int out_size, void* d_ws, size_t ws_size,
                              hipStream_t stream)
{
  (void)in_sizes; (void)n_in; (void)out_size; (void)ws_size;
  const float* x     = (const float*)d_in[0];
  const void*  ei    = (const void*)d_in[1];
  const float* W1l   = (const float*)d_in[2];
  const float* W1r   = (const float*)d_in[3];
  const float* att1  = (const float*)d_in[4];
  const float* b1    = (const float*)d_in[5];
  const float* W2l   = (const float*)d_in[6];
  const float* W2r   = (const float*)d_in[7];
  const float* att2  = (const float*)d_in[8];
  const float* b2    = (const float*)d_in[9];
  const float* pw1   = (const float*)d_in[10];
  const float* pb1   = (const float*)d_in[11];
  const float* gamma = (const float*)d_in[12];
  const float* beta  = (const float*)d_in[13];
  const float* pw2   = (const float*)d_in[14];
  const float* pb2   = (const float*)d_in[15];

  char* ws = (char*)d_ws;
  unsigned short* H1b   = (unsigned short*)(ws + 0);           // [N][512] bf16, 51.2 MB
  unsigned short* h1b   = (unsigned short*)(ws + 51200000);    // [N][256] bf16
  unsigned short* H2b   = (unsigned short*)(ws + 76800000);    // [N][256] bf16
  unsigned short* h2b   = (unsigned short*)(ws + 102400000);   // [N][128] bf16
  float*          tbuf  = (float*)(ws + 115200000);            // [N][128] fp32
  unsigned short* ybuf  = (unsigned short*)(ws + 140800000);   // [N][128] bf16
  int*            rowptr = (int*)(ws + 153600000);             // 50001*4
  int*            cnt    = (int*)(ws + 153800192);             // 50000*4
  int*            colv   = (int*)(ws + 154000384);             // 850000*4
  unsigned short* WT1    = (unsigned short*)(ws + 157400384);  // [512][2048]
  unsigned short* WT2    = (unsigned short*)(ws + 159497536);  // [256][256]
  unsigned short* PT1    = (unsigned short*)(ws + 159628608);  // [128][128]
  unsigned short* PT2    = (unsigned short*)(ws + 159661376);  // [128][128]
  float*          bnsum  = (float*)(ws + 159694144);
  float*          bnp    = (float*)(ws + 159695168);
  int*            eflag  = (int*)(ws + 159696192);

  hipMemsetAsync(cnt, 0, 200000, stream);
  hipMemsetAsync(bnsum, 0, 1024, stream);

  detect_i64<<<1, 64, 0, stream>>>(ei, eflag);
  wt_cvt<<<dim3(8, 512), 256, 0, stream>>>(W1l, W1r, WT1, 2048, 256);
  wt_cvt<<<dim3(1, 256), 256, 0, stream>>>(W2l, W2r, WT2, 256, 128);
  wt_cvt<<<dim3(1, 128), 256, 0, stream>>>(pw1, pw1, PT1, 128, 128);
  wt_cvt<<<dim3(1, 128), 256, 0, stream>>>(pw2, pw2, PT2, 128, 128);

  const int ebl = (ETOT + 255) / 256;
  csr_hist<<<ebl, 256, 0, stream>>>(ei, eflag, cnt);
  csr_scan<<<1, 1024, 0, stream>>>(cnt, rowptr);
  hipMemsetAsync(cnt, 0, 200000, stream);
  csr_scatter<<<ebl, 256, 0, stream>>>(ei, eflag, rowptr, cnt, colv);

  const int nby = (NN + 127) / 128;   // 391
  // conv1: H1 = x @ [W1l|W1r]  (A fp32 via cvt_pk path), out bf16
  gemm_t<false><<<nby * 4, 256, 0, stream>>>(x, WT1, H1b, nullptr, NN, 2048, 512, 1, 4, nby * 4);
  node_conv1<<<(NN + 3) / 4, 256, 0, stream>>>(H1b, rowptr, colv, att1, b1, h1b);

  // conv2: H2 = h1 @ [W2l|W2r]  (A bf16), out bf16
  gemm_t<true><<<nby * 2, 256, 0, stream>>>(h1b, WT2, H2b, nullptr, NN, 256, 256, 1, 2, nby * 2);
  node_conv2<<<(NN + 3) / 4, 256, 0, stream>>>(H2b, rowptr, colv, att2, b2, h2b);

  // projection head
  gemm_t<true><<<nby, 256, 0, stream>>>(h2b, PT1, tbuf, pb1, NN, 128, 128, 0, 1, nby);
  bn_stats<<<(NN + SROWS - 1) / SROWS, 256, 0, stream>>>(tbuf, bnsum, NN);
  bn_final<<<1, 128, 0, stream>>>(bnsum, gamma, beta, bnp, NN);
  bn_apply<<<(NN * 128 + 255) / 256, 256, 0, stream>>>(tbuf, bnp, ybuf, NN * 128);

  // final linear -> fp32 out
  gemm_t<true><<<nby, 256, 0, stream>>>(ybuf, PT2, (float*)d_out, pb2, NN, 128, 128, 0, 1, nby);
}

// Round 6
// 733.305 us; speedup vs baseline: 2.9708x; 1.0317x over previous
//
#include <hip/hip_runtime.h>
#include <hip/hip_bf16.h>
#include <cstdint>
#include <cstddef>

#define NN 50000
#define NE 800000
#define ETOT (NN + NE)   // 850000 edges incl. self loops

typedef float f32x4 __attribute__((ext_vector_type(4)));
typedef short s16x8 __attribute__((ext_vector_type(8)));

__device__ __forceinline__ unsigned short f2bf(float f) {
  unsigned u = __float_as_uint(f);
  u += 0x7FFFu + ((u >> 16) & 1u);   // RNE
  return (unsigned short)(u >> 16);
}
__device__ __forceinline__ float bf2f(unsigned short u) {
  return __uint_as_float(((unsigned)u) << 16);
}
__device__ __forceinline__ unsigned cvtpk(float lo, float hi) {  // 2xf32 -> packed bf16 (RNE)
  unsigned r;
  asm("v_cvt_pk_bf16_f32 %0, %1, %2" : "=v"(r) : "v"(lo), "v"(hi));
  return r;
}
typedef const __attribute__((address_space(1))) void* gas_t;
typedef __attribute__((address_space(3))) void* las_t;
__device__ __forceinline__ void gload_lds16(const void* g, void* l) {
  __builtin_amdgcn_global_load_lds((gas_t)g, (las_t)l, 16, 0, 0);
}

// edge_index may arrive as int32 or int64; detect on device (deterministic input).
__global__ void detect_i64(const void* __restrict__ ei, int* __restrict__ flag) {
  const long long v = ((const long long*)ei)[threadIdx.x];
  const bool ok = (v >= 0 && v < NN);
  const unsigned long long m = __ballot(ok);
  if (threadIdx.x == 0) *flag = (m == ~0ULL) ? 1 : 0;
}
__device__ __forceinline__ void load_edge(const void* __restrict__ ei, int is64,
                                          int eidx, int& src, int& dst) {
  if (eidx >= NE) { src = dst = eidx - NE; return; }
  if (is64) {
    src = (int)((const long long*)ei)[eidx];
    dst = (int)((const long long*)ei)[NE + eidx];
  } else {
    src = ((const int*)ei)[eidx];
    dst = ((const int*)ei)[NE + eidx];
  }
}

// ---------------- CSR build (by dst) ----------------
__global__ __launch_bounds__(256) void csr_hist(
    const void* __restrict__ ei, const int* __restrict__ flag, int* __restrict__ cnt)
{
  const int e = blockIdx.x * 256 + threadIdx.x;
  if (e >= ETOT) return;
  int src, dst;
  load_edge(ei, *flag, e, src, dst);
  atomicAdd(&cnt[dst], 1);
}

// shfl-based scan: 3 barriers per 1024-chunk (was ~20 with the ladder scan)
__global__ __launch_bounds__(1024) void csr_scan(
    const int* __restrict__ cnt, int* __restrict__ rowptr)
{
  __shared__ int wsum[16];
  const int tid = threadIdx.x, lane = tid & 63, w = tid >> 6;
  int run = 0;
  if (tid == 0) rowptr[0] = 0;
  for (int base = 0; base < NN; base += 1024) {
    int s = (base + tid < NN) ? cnt[base + tid] : 0;
    #pragma unroll
    for (int off = 1; off < 64; off <<= 1) {
      int t = __shfl_up(s, off);
      if (lane >= off) s += t;
    }
    if (lane == 63) wsum[w] = s;
    __syncthreads();
    if (w == 0) {
      int ws = (lane < 16) ? wsum[lane] : 0;
      #pragma unroll
      for (int off = 1; off < 16; off <<= 1) {
        int t = __shfl_up(ws, off);
        if (lane >= off) ws += t;
      }
      if (lane < 16) wsum[lane] = ws;
    }
    __syncthreads();
    const int woff = (w > 0) ? wsum[w - 1] : 0;
    if (base + tid < NN) rowptr[base + tid + 1] = run + woff + s;
    run += wsum[15];
    __syncthreads();
  }
}

__global__ __launch_bounds__(256) void csr_scatter(
    const void* __restrict__ ei, const int* __restrict__ flag,
    const int* __restrict__ rowptr, int* __restrict__ cur, int* __restrict__ colv)
{
  const int e = blockIdx.x * 256 + threadIdx.x;
  if (e >= ETOT) return;
  int src, dst;
  load_edge(ei, *flag, e, src, dst);
  const int pos = atomicAdd(&cur[dst], 1);
  colv[rowptr[dst] + pos] = src;
}

// ---------------- GEMM: C[M][Nc] = A[M][K] @ BT[Nc][K]^T (+bias) ----------------
// 128x128 tile, 4 waves, BK=32, DOUBLE-BUFFERED LDS, one barrier per K-step
// (T3 minimum-2-phase: stage t+1 issued before compute of t). fp32-A path loads
// regs at loop top (T14 issue-early), cvt_pk+ds_write after the MFMAs.
// Optional abn (fp32 path): A-element v = relu(v*abn[k] + abn[K+k]) — fused BN.
template<bool ABF16>
__global__ __launch_bounds__(256) void gemm_t(
    const void* __restrict__ Av, const unsigned short* __restrict__ BT,
    void* __restrict__ Cv, const float* __restrict__ bias,
    const float* __restrict__ abn,
    int M, int K, int Ncols, int out_bf16, int nbx, int nwg)
{
  __shared__ unsigned short As[2][128 * 32];
  __shared__ unsigned short Bs[2][128 * 32];

  int bid = blockIdx.x;
  {  // bijective XCD-chunked swizzle (m204)
    const int q = nwg >> 3, r = nwg & 7;
    const int xcd = bid & 7, idx = bid >> 3;
    bid = (xcd < r ? xcd * (q + 1) : r * (q + 1) + (xcd - r) * q) + idx;
  }
  const int bx = bid % nbx, by = bid / nbx;
  const int row0 = by * 128, col0 = bx * 128;
  const int tid = threadIdx.x, wave = tid >> 6, lane = tid & 63;
  const int l16 = lane & 15, lq = lane >> 4;
  const int wr = wave >> 1, wc = wave & 1;

  // staging: chunk c in [0,512) = (row=c>>2, part=c&3, 8 ushorts); thread: {tid, tid+256}
  const int c0 = tid, c1 = tid + 256;
  int ar0 = row0 + (c0 >> 2); if (ar0 >= M) ar0 = M - 1;
  int ar1 = row0 + (c1 >> 2); if (ar1 >= M) ar1 = M - 1;
  const int ap0 = (c0 & 3) * 8, ap1 = (c1 & 3) * 8;
  const int br0 = col0 + (c0 >> 2), br1 = col0 + (c1 >> 2);
  const unsigned short* Ab = (const unsigned short*)Av;
  const float*          Af = (const float*)Av;

  f32x4 acc[4][4];
  #pragma unroll
  for (int i = 0; i < 4; ++i)
    #pragma unroll
    for (int j = 0; j < 4; ++j)
      #pragma unroll
      for (int r = 0; r < 4; ++r) acc[i][j][r] = 0.f;

  const int nt = K >> 5;
  float4 a0, a1, a2, a3;   // fp32-A in-flight staging regs

  auto aload = [&](int koff) {
    a0 = *(const float4*)(Af + (size_t)ar0 * K + koff + ap0);
    a1 = *(const float4*)(Af + (size_t)ar0 * K + koff + ap0 + 4);
    a2 = *(const float4*)(Af + (size_t)ar1 * K + koff + ap1);
    a3 = *(const float4*)(Af + (size_t)ar1 * K + koff + ap1 + 4);
  };
  auto astore = [&](int buf, int koff) {
    if (abn) {
      const int k0a = koff + ap0, k1a = koff + ap1;
      a0.x = fmaxf(a0.x * abn[k0a]     + abn[K + k0a],     0.f);
      a0.y = fmaxf(a0.y * abn[k0a + 1] + abn[K + k0a + 1], 0.f);
      a0.z = fmaxf(a0.z * abn[k0a + 2] + abn[K + k0a + 2], 0.f);
      a0.w = fmaxf(a0.w * abn[k0a + 3] + abn[K + k0a + 3], 0.f);
      a1.x = fmaxf(a1.x * abn[k0a + 4] + abn[K + k0a + 4], 0.f);
      a1.y = fmaxf(a1.y * abn[k0a + 5] + abn[K + k0a + 5], 0.f);
      a1.z = fmaxf(a1.z * abn[k0a + 6] + abn[K + k0a + 6], 0.f);
      a1.w = fmaxf(a1.w * abn[k0a + 7] + abn[K + k0a + 7], 0.f);
      a2.x = fmaxf(a2.x * abn[k1a]     + abn[K + k1a],     0.f);
      a2.y = fmaxf(a2.y * abn[k1a + 1] + abn[K + k1a + 1], 0.f);
      a2.z = fmaxf(a2.z * abn[k1a + 2] + abn[K + k1a + 2], 0.f);
      a2.w = fmaxf(a2.w * abn[k1a + 3] + abn[K + k1a + 3], 0.f);
      a3.x = fmaxf(a3.x * abn[k1a + 4] + abn[K + k1a + 4], 0.f);
      a3.y = fmaxf(a3.y * abn[k1a + 5] + abn[K + k1a + 5], 0.f);
      a3.z = fmaxf(a3.z * abn[k1a + 6] + abn[K + k1a + 6], 0.f);
      a3.w = fmaxf(a3.w * abn[k1a + 7] + abn[K + k1a + 7], 0.f);
    }
    uint4 w0, w1;
    w0.x = cvtpk(a0.x, a0.y); w0.y = cvtpk(a0.z, a0.w);
    w0.z = cvtpk(a1.x, a1.y); w0.w = cvtpk(a1.z, a1.w);
    w1.x = cvtpk(a2.x, a2.y); w1.y = cvtpk(a2.z, a2.w);
    w1.z = cvtpk(a3.x, a3.y); w1.w = cvtpk(a3.z, a3.w);
    *(uint4*)&As[buf][c0 * 8] = w0;
    *(uint4*)&As[buf][c1 * 8] = w1;
  };

  // prologue: stage tile 0 into buf 0
  if (ABF16) {
    gload_lds16(Ab + (size_t)ar0 * K + ap0, &As[0][c0 * 8]);
    gload_lds16(Ab + (size_t)ar1 * K + ap1, &As[0][c1 * 8]);
  } else {
    aload(0);
  }
  gload_lds16(BT + (size_t)br0 * K + ap0, &Bs[0][c0 * 8]);
  gload_lds16(BT + (size_t)br1 * K + ap1, &Bs[0][c1 * 8]);
  if (!ABF16) astore(0, 0);
  __syncthreads();

  for (int t = 0; t < nt; ++t) {
    const int cur = t & 1, nxt = cur ^ 1;
    const int k1 = (t + 1) << 5;
    const bool more = (t + 1 < nt);
    if (more) {   // issue next tile's loads BEFORE computing current
      if (ABF16) {
        gload_lds16(Ab + (size_t)ar0 * K + k1 + ap0, &As[nxt][c0 * 8]);
        gload_lds16(Ab + (size_t)ar1 * K + k1 + ap1, &As[nxt][c1 * 8]);
      } else {
        aload(k1);
      }
      gload_lds16(BT + (size_t)br0 * K + k1 + ap0, &Bs[nxt][c0 * 8]);
      gload_lds16(BT + (size_t)br1 * K + k1 + ap1, &Bs[nxt][c1 * 8]);
    }
    s16x8 af[4], bf[4];
    #pragma unroll
    for (int f = 0; f < 4; ++f)
      af[f] = *(const s16x8*)&As[cur][(wr * 64 + f * 16 + l16) * 32 + lq * 8];
    #pragma unroll
    for (int f = 0; f < 4; ++f)
      bf[f] = *(const s16x8*)&Bs[cur][(wc * 64 + f * 16 + l16) * 32 + lq * 8];
    #pragma unroll
    for (int fm = 0; fm < 4; ++fm)
      #pragma unroll
      for (int fn = 0; fn < 4; ++fn)
        acc[fm][fn] = __builtin_amdgcn_mfma_f32_16x16x32_bf16(af[fm], bf[fn], acc[fm][fn], 0, 0, 0);
    if (!ABF16 && more) astore(nxt, k1);   // write-late: after MFMAs
    __syncthreads();   // drains vmcnt+lgkm: buf nxt ready, buf cur reads retired
  }

  float bv[4];
  #pragma unroll
  for (int fn = 0; fn < 4; ++fn)
    bv[fn] = bias ? bias[col0 + wc * 64 + fn * 16 + l16] : 0.f;

  // C/D layout: col = l16, row = lq*4 + r (verified m89/m91 + rounds 2-4)
  #pragma unroll
  for (int fm = 0; fm < 4; ++fm) {
    #pragma unroll
    for (int r = 0; r < 4; ++r) {
      const int row = row0 + wr * 64 + fm * 16 + lq * 4 + r;
      if (row < M) {
        #pragma unroll
        for (int fn = 0; fn < 4; ++fn) {
          const int col = col0 + wc * 64 + fn * 16 + l16;
          const float v = acc[fm][fn][r] + bv[fn];
          if (out_bf16) ((unsigned short*)Cv)[(size_t)row * Ncols + col] = f2bf(v);
          else          ((float*)Cv)[(size_t)row * Ncols + col] = v;
        }
      }
    }
  }
}

// ---------------- fused per-node GATv2 (online softmax + aggregate), bf16 I/O ----
// conv1: 4 heads x 64ch. H1=[N][512] bf16. Wave per node; lane = (head=lane>>4, 4ch).
__global__ __launch_bounds__(256) void node_conv1(
    const unsigned short* __restrict__ H1, const int* __restrict__ rowptr,
    const int* __restrict__ colv, const float* __restrict__ att,
    const float* __restrict__ b1, unsigned short* __restrict__ out)
{
  const int node = blockIdx.x * 4 + (threadIdx.x >> 6);
  if (node >= NN) return;
  const int lane = threadIdx.x & 63;
  const int base4 = lane * 4;
  float xr[4], at[4];
  {
    const ushort4 t = *(const ushort4*)&H1[(size_t)node * 512 + 256 + base4];
    xr[0] = bf2f(t.x); xr[1] = bf2f(t.y); xr[2] = bf2f(t.z); xr[3] = bf2f(t.w);
    at[0] = att[base4]; at[1] = att[base4 + 1]; at[2] = att[base4 + 2]; at[3] = att[base4 + 3];
  }
  float m = -1e30f, s = 0.f, a0 = 0.f, a1 = 0.f, a2 = 0.f, a3 = 0.f;
  const int beg = rowptr[node], end = rowptr[node + 1];
  ushort4 xa = *(const ushort4*)&H1[(size_t)colv[beg] * 512 + base4];
  ushort4 xb = (beg + 1 < end) ? *(const ushort4*)&H1[(size_t)colv[beg + 1] * 512 + base4] : xa;
  for (int i = beg; i < end; ++i) {
    const int ip2 = (i + 2 < end) ? i + 2 : end - 1;
    const ushort4 xc = *(const ushort4*)&H1[(size_t)colv[ip2] * 512 + base4];  // depth-2 prefetch
    const float x0 = bf2f(xa.x), x1 = bf2f(xa.y), x2 = bf2f(xa.z), x3 = bf2f(xa.w);
    float mm, e = 0.f;
    mm = x0 + xr[0]; mm = mm > 0.f ? mm : 0.2f * mm; e += mm * at[0];
    mm = x1 + xr[1]; mm = mm > 0.f ? mm : 0.2f * mm; e += mm * at[1];
    mm = x2 + xr[2]; mm = mm > 0.f ? mm : 0.2f * mm; e += mm * at[2];
    mm = x3 + xr[3]; mm = mm > 0.f ? mm : 0.2f * mm; e += mm * at[3];
    e += __shfl_xor(e, 1); e += __shfl_xor(e, 2);
    e += __shfl_xor(e, 4); e += __shfl_xor(e, 8);   // 16-lane group = one head
    const float mn = fmaxf(m, e);
    const float sc = __expf(m - mn);
    const float w  = __expf(e - mn);
    s = s * sc + w;
    a0 = a0 * sc + w * x0; a1 = a1 * sc + w * x1;
    a2 = a2 * sc + w * x2; a3 = a3 * sc + w * x3;
    m = mn;
    xa = xb; xb = xc;
  }
  const float inv = 1.f / s;
  ushort4 o;
  o.x = f2bf(fmaxf(a0 * inv + b1[base4],     0.f));
  o.y = f2bf(fmaxf(a1 * inv + b1[base4 + 1], 0.f));
  o.z = f2bf(fmaxf(a2 * inv + b1[base4 + 2], 0.f));
  o.w = f2bf(fmaxf(a3 * inv + b1[base4 + 3], 0.f));
  *(ushort4*)&out[(size_t)node * 256 + base4] = o;
}

// conv2: 1 head x 128ch. H2=[N][256] bf16. Wave per node; lane = 2 channels.
__global__ __launch_bounds__(256) void node_conv2(
    const unsigned short* __restrict__ H2, const int* __restrict__ rowptr,
    const int* __restrict__ colv, const float* __restrict__ att,
    const float* __restrict__ b2, unsigned short* __restrict__ out)
{
  const int node = blockIdx.x * 4 + (threadIdx.x >> 6);
  if (node >= NN) return;
  const int lane = threadIdx.x & 63;
  const int c2 = lane * 2;
  float xr0, xr1, at0, at1;
  {
    const ushort2 t = *(const ushort2*)&H2[(size_t)node * 256 + 128 + c2];
    xr0 = bf2f(t.x); xr1 = bf2f(t.y);
    at0 = att[c2]; at1 = att[c2 + 1];
  }
  float m = -1e30f, s = 0.f, a0 = 0.f, a1 = 0.f;
  const int beg = rowptr[node], end = rowptr[node + 1];
  ushort2 xa = *(const ushort2*)&H2[(size_t)colv[beg] * 256 + c2];
  ushort2 xb = (beg + 1 < end) ? *(const ushort2*)&H2[(size_t)colv[beg + 1] * 256 + c2] : xa;
  for (int i = beg; i < end; ++i) {
    const int ip2 = (i + 2 < end) ? i + 2 : end - 1;
    const ushort2 xc = *(const ushort2*)&H2[(size_t)colv[ip2] * 256 + c2];
    const float x0 = bf2f(xa.x), x1 = bf2f(xa.y);
    float mm, e = 0.f;
    mm = x0 + xr0; mm = mm > 0.f ? mm : 0.2f * mm; e += mm * at0;
    mm = x1 + xr1; mm = mm > 0.f ? mm : 0.2f * mm; e += mm * at1;
    #pragma unroll
    for (int off = 32; off > 0; off >>= 1) e += __shfl_xor(e, off);
    const float mn = fmaxf(m, e);
    const float sc = __expf(m - mn);
    const float w  = __expf(e - mn);
    s = s * sc + w;
    a0 = a0 * sc + w * x0; a1 = a1 * sc + w * x1;
    m = mn;
    xa = xb; xb = xc;
  }
  const float inv = 1.f / s;
  ushort2 o;
  o.x = f2bf(a0 * inv + b2[c2]);
  o.y = f2bf(a1 * inv + b2[c2 + 1]);
  *(ushort2*)&out[(size_t)node * 128 + c2] = o;
}

// ---------------- misc ----------------
__global__ __launch_bounds__(256) void wt_cvt(
    const float* __restrict__ Wa, const float* __restrict__ Wb,
    unsigned short* __restrict__ dst, int K, int halfN)
{
  const int k = blockIdx.x * 256 + threadIdx.x;
  const int n = blockIdx.y;
  if (k >= K) return;
  const float v = (n < halfN) ? Wa[(size_t)k * halfN + n]
                              : Wb[(size_t)k * halfN + (n - halfN)];
  dst[(size_t)n * K + k] = f2bf(v);
}

#define SROWS 256
__global__ __launch_bounds__(256) void bn_stats(
    const float* __restrict__ t, float* __restrict__ sums, int M)
{
  const int tid = threadIdx.x;
  const int c = tid & 127, half = tid >> 7;
  const int r0 = blockIdx.x * SROWS;
  int rend = r0 + SROWS; if (rend > M) rend = M;
  float s = 0.f, q = 0.f;
  for (int r = r0 + half; r < rend; r += 2) {
    const float v = t[(size_t)r * 128 + c];
    s += v; q += v * v;
  }
  __shared__ float ls[256], lq[256];
  ls[tid] = s; lq[tid] = q;
  __syncthreads();
  if (tid < 128) {
    atomicAdd(&sums[c],       ls[tid] + ls[tid + 128]);
    atomicAdd(&sums[128 + c], lq[tid] + lq[tid + 128]);
  }
}

__global__ void bn_final(const float* __restrict__ sums, const float* __restrict__ gamma,
                         const float* __restrict__ beta, float* __restrict__ bnp, int M)
{
  const int c = threadIdx.x;
  if (c < 128) {
    const float mu  = sums[c] / (float)M;
    const float var = sums[128 + c] / (float)M - mu * mu;
    const float sc  = gamma[c] * rsqrtf(var + 1e-5f);
    bnp[c] = sc;
    bnp[128 + c] = beta[c] - mu * sc;
  }
}

// ---------------- launch ----------------
extern "C" void kernel_launch(void* const* d_in, const int* in_sizes, int n_in,
                              void* d_out, int out_size, void* d_ws, size_t ws_size,
                              hipStream_t stream)
{
  (void)in_sizes; (void)n_in; (void)out_size; (void)ws_size;
  const float* x     = (const float*)d_in[0];
  const void*  ei    = (const void*)d_in[1];
  const float* W1l   = (const float*)d_in[2];
  const float* W1r   = (const float*)d_in[3];
  const float* att1  = (const float*)d_in[4];
  const float* b1    = (const float*)d_in[5];
  const float* W2l   = (const float*)d_in[6];
  const float* W2r   = (const float*)d_in[7];
  const float* att2  = (const float*)d_in[8];
  const float* b2    = (const float*)d_in[9];
  const float* pw1   = (const float*)d_in[10];
  const float* pb1   = (const float*)d_in[11];
  const float* gamma = (const float*)d_in[12];
  const float* beta  = (const float*)d_in[13];
  const float* pw2   = (const float*)d_in[14];
  const float* pb2   = (const float*)d_in[15];

  char* ws = (char*)d_ws;
  unsigned short* H1b   = (unsigned short*)(ws + 0);           // [N][512] bf16
  unsigned short* h1b   = (unsigned short*)(ws + 51200000);    // [N][256] bf16
  unsigned short* H2b   = (unsigned short*)(ws + 76800000);    // [N][256] bf16
  unsigned short* h2b   = (unsigned short*)(ws + 102400000);   // [N][128] bf16
  float*          tbuf  = (float*)(ws + 115200000);            // [N][128] fp32
  int*            rowptr = (int*)(ws + 153600000);             // 50001*4
  int*            cnt    = (int*)(ws + 153800192);             // 50000*4
  int*            colv   = (int*)(ws + 154000384);             // 850000*4
  unsigned short* WT1    = (unsigned short*)(ws + 157400384);  // [512][2048]
  unsigned short* WT2    = (unsigned short*)(ws + 159497536);  // [256][256]
  unsigned short* PT1    = (unsigned short*)(ws + 159628608);  // [128][128]
  unsigned short* PT2    = (unsigned short*)(ws + 159661376);  // [128][128]
  float*          bnsum  = (float*)(ws + 159694144);
  float*          bnp    = (float*)(ws + 159695168);
  int*            eflag  = (int*)(ws + 159696192);

  hipMemsetAsync(cnt, 0, 200000, stream);
  hipMemsetAsync(bnsum, 0, 1024, stream);

  detect_i64<<<1, 64, 0, stream>>>(ei, eflag);
  wt_cvt<<<dim3(8, 512), 256, 0, stream>>>(W1l, W1r, WT1, 2048, 256);
  wt_cvt<<<dim3(1, 256), 256, 0, stream>>>(W2l, W2r, WT2, 256, 128);
  wt_cvt<<<dim3(1, 128), 256, 0, stream>>>(pw1, pw1, PT1, 128, 128);
  wt_cvt<<<dim3(1, 128), 256, 0, stream>>>(pw2, pw2, PT2, 128, 128);

  const int ebl = (ETOT + 255) / 256;
  csr_hist<<<ebl, 256, 0, stream>>>(ei, eflag, cnt);
  csr_scan<<<1, 1024, 0, stream>>>(cnt, rowptr);
  hipMemsetAsync(cnt, 0, 200000, stream);
  csr_scatter<<<ebl, 256, 0, stream>>>(ei, eflag, rowptr, cnt, colv);

  const int nby = (NN + 127) / 128;   // 391
  // conv1: H1 = x @ [W1l|W1r]  (A fp32, dbuf + early-issue), out bf16
  gemm_t<false><<<nby * 4, 256, 0, stream>>>(x, WT1, H1b, nullptr, nullptr, NN, 2048, 512, 1, 4, nby * 4);
  node_conv1<<<(NN + 3) / 4, 256, 0, stream>>>(H1b, rowptr, colv, att1, b1, h1b);

  // conv2: H2 = h1 @ [W2l|W2r]  (A bf16), out bf16
  gemm_t<true><<<nby * 2, 256, 0, stream>>>(h1b, WT2, H2b, nullptr, nullptr, NN, 256, 256, 1, 2, nby * 2);
  node_conv2<<<(NN + 3) / 4, 256, 0, stream>>>(H2b, rowptr, colv, att2, b2, h2b);

  // projection head: proj1 -> BN stats -> proj2 (BN affine+ReLU fused into A-staging)
  gemm_t<true><<<nby, 256, 0, stream>>>(h2b, PT1, tbuf, pb1, nullptr, NN, 128, 128, 0, 1, nby);
  bn_stats<<<(NN + SROWS - 1) / SROWS, 256, 0, stream>>>(tbuf, bnsum, NN);
  bn_final<<<1, 128, 0, stream>>>(bnsum, gamma, beta, bnp, NN);
  gemm_t<false><<<nby, 256, 0, stream>>>(tbuf, PT2, (float*)d_out, pb2, bnp, NN, 128, 128, 0, 1, nby);
}